// Round 18
// baseline (148.283 us; speedup 1.0000x reference)
//
#include <hip/hip_runtime.h>
#include <hip/hip_bf16.h>
#include <math.h>

typedef __attribute__((ext_vector_type(8))) short bf16x8;
typedef __attribute__((ext_vector_type(4))) float f32x4;
typedef __attribute__((ext_vector_type(16))) float f32x16;

#define B_ 8
#define S_ 1024
#define E_ 128
#define H_ 16
#define M_ (B_*S_)
#define F_ (3*H_*E_)

__device__ __forceinline__ unsigned short f2b(float x) {
  __hip_bfloat16 h = __float2bfloat16(x);
  return *reinterpret_cast<unsigned short*>(&h);
}

__device__ __forceinline__ f32x4 mfma16(bf16x8 a, bf16x8 b, f32x4 c) {
  return __builtin_amdgcn_mfma_f32_16x16x32_bf16(a, b, c, 0, 0, 0);
}
__device__ __forceinline__ f32x16 mfma32(bf16x8 a, bf16x8 b, f32x16 c) {
  return __builtin_amdgcn_mfma_f32_32x32x16_bf16(a, b, c, 0, 0, 0);
}
__device__ __forceinline__ unsigned cvtpk(float a, float b) {
  unsigned r; asm("v_cvt_pk_bf16_f32 %0, %1, %2" : "=v"(r) : "v"(a), "v"(b)); return r;
}

// ---------------- prep: fp32->bf16 + rope tables ----------------
__global__ __launch_bounds__(256) void prep_kernel(
    const float* __restrict__ seq, const float* __restrict__ wq,
    unsigned short* __restrict__ seqb, unsigned short* __restrict__ wb,
    float* __restrict__ ctab, float* __restrict__ stab)
{
  int i = blockIdx.x * 256 + threadIdx.x;
  if (i < M_*E_/4) {
    float4 v = reinterpret_cast<const float4*>(seq)[i];
    ushort4 o; o.x = f2b(v.x); o.y = f2b(v.y); o.z = f2b(v.z); o.w = f2b(v.w);
    reinterpret_cast<ushort4*>(seqb)[i] = o;
  }
  if (i < F_*E_/4) {
    float4 v = reinterpret_cast<const float4*>(wq)[i];
    ushort4 o; o.x = f2b(v.x); o.y = f2b(v.y); o.z = f2b(v.z); o.w = f2b(v.w);
    reinterpret_cast<ushort4*>(wb)[i] = o;
  }
  if (i < S_*64) {
    int s = i >> 6, e = i & 63;
    double ang = (double)s * pow(10000.0, -(double)e / 64.0);
    ctab[i] = (float)cos(ang);
    stab[i] = (float)sin(ang);
  }
}

// ---------------- QKV GEMM + bias + rope -> Q,K (B,H,S,E), V^T (B,H,E,S) ----------------
// K pre-scaled by (1/sqrt(128)) * log2(e) so attention uses exp2 directly.
// V^T stored with kv-index bits 2<->3 swapped within each aligned 32-group (exchange-free PV repack).
__global__ __launch_bounds__(256) void qkv_gemm_kernel(
    const unsigned short* __restrict__ Ab, const unsigned short* __restrict__ Wb,
    const float* __restrict__ bias, const float* __restrict__ ctab, const float* __restrict__ stab,
    unsigned short* __restrict__ qo, unsigned short* __restrict__ ko, unsigned short* __restrict__ vt)
{
  __shared__ union QSMem {
    struct { unsigned short A[128*128]; unsigned short W[128*128]; } s;  // 64 KB, GEMM phase
    unsigned short Tp[128][136];                                         // 34.8 KB, V-transpose
  } sm;
  const int bm = blockIdx.x, bn = blockIdx.y;
  const int t = threadIdx.x;
  const int w = t >> 6, l = t & 63, lc = l & 15, g = l >> 4;

  #pragma unroll
  for (int i = 0; i < 8; ++i) {
    int c = i*256 + t;
    int row = c >> 4, cb = c & 15;
    int sb = (cb & 8) | ((cb ^ row) & 7);
    __builtin_amdgcn_global_load_lds(
      (const __attribute__((address_space(1))) void*)(Ab + (size_t)(bm*128+row)*128 + sb*8),
      (__attribute__((address_space(3))) void*)(&sm.s.A[c*8]), 16, 0, 0);
    __builtin_amdgcn_global_load_lds(
      (const __attribute__((address_space(1))) void*)(Wb + (size_t)(bn*128+row)*128 + sb*8),
      (__attribute__((address_space(3))) void*)(&sm.s.W[c*8]), 16, 0, 0);
  }
  __syncthreads();

  const f32x4 zero = {0.f, 0.f, 0.f, 0.f};
  f32x4 acc[2][8];
  #pragma unroll
  for (int mi=0;mi<2;mi++)
    #pragma unroll
    for (int nj=0;nj<8;nj++) acc[mi][nj] = zero;

  #pragma unroll
  for (int ks = 0; ks < 4; ++ks) {
    const int B0 = ks*4 + g;
    const int slot = (B0 & 8) | ((B0 ^ lc) & 7);
    bf16x8 a[2], b[8];
    #pragma unroll
    for (int mi=0;mi<2;mi++)
      a[mi] = *reinterpret_cast<const bf16x8*>(&sm.s.A[(w*32 + mi*16 + lc)*128 + slot*8]);
    #pragma unroll
    for (int nj=0;nj<8;nj++)
      b[nj] = *reinterpret_cast<const bf16x8*>(&sm.s.W[(nj*16 + lc)*128 + slot*8]);
    #pragma unroll
    for (int mi=0;mi<2;mi++)
      #pragma unroll
      for (int nj=0;nj<8;nj++)
        acc[mi][nj] = mfma16(a[mi], b[nj], acc[mi][nj]);
  }

  float bv[8];
  #pragma unroll
  for (int nj=0;nj<8;nj++) bv[nj] = bias[bn*128 + nj*16 + lc];

  const int c3 = bn >> 4, h = bn & 15;
  if (c3 < 2) {
    unsigned short* dst = (c3 == 0) ? qo : ko;
    const float mul = (c3 == 1) ? 0.12751742f : 1.0f;
    #pragma unroll
    for (int mi=0;mi<2;mi++)
      #pragma unroll
      for (int r=0;r<4;r++) {
        int mrow = bm*128 + w*32 + mi*16 + g*4 + r;
        int bb = mrow >> 10, s = mrow & 1023;
        size_t ob = ((size_t)(bb*H_ + h)*S_ + s)*E_;
        #pragma unroll
        for (int nj=0;nj<4;nj++) {
          int e1 = nj*16 + lc;
          float x1 = acc[mi][nj][r]   + bv[nj];
          float x2 = acc[mi][nj+4][r] + bv[nj+4];
          float cs = ctab[s*64 + e1], sn = stab[s*64 + e1];
          dst[ob + e1]      = f2b((x1*cs - x2*sn) * mul);
          dst[ob + e1 + 64] = f2b((x1*sn + x2*cs) * mul);
        }
      }
  } else {
    __syncthreads();
    const int gsw = ((g & 1) << 1) | (g >> 1);   // swap kv bits 2<->3 (within 32-group)
    #pragma unroll
    for (int mi=0;mi<2;mi++)
      #pragma unroll
      for (int nj=0;nj<8;nj++)
        #pragma unroll
        for (int r=0;r<4;r++)
          sm.Tp[nj*16 + lc][w*32 + mi*16 + gsw*4 + r] = f2b(acc[mi][nj][r] + bv[nj]);
    __syncthreads();
    int bb = bm >> 3, sb2 = (bm & 7) * 128;
    #pragma unroll
    for (int i=0;i<8;i++) {
      int cidx = t + i*256, e = cidx >> 4, sc = cidx & 15;
      *reinterpret_cast<bf16x8*>(&vt[((size_t)(bb*H_ + h)*E_ + e)*S_ + sb2 + sc*8]) =
          *reinterpret_cast<const bf16x8*>(&sm.Tp[e][sc*8]);
    }
  }
}

// ---------------- flash attention: 4 waves x 64 q-rows, KVBLK=32, static-max softmax ----------------
// R17 tile body VERBATIM; only buffering changed: 4 buffers, 2 tiles per barrier (16 barriers).
__global__ __launch_bounds__(256, 2) void attn_kernel(
    const unsigned short* __restrict__ qg, const unsigned short* __restrict__ kg,
    const unsigned short* __restrict__ vtg, float* __restrict__ out)
{
  __shared__ union SMem {
    struct { unsigned short Ks[4][32*128]; unsigned short Vs[4][128*32]; } kv;  // 65536 B, main loop
    float Tr[4][32][132];                                                       // 67584 B, epilogue
  } smem;
  const int bh = blockIdx.x, qb = blockIdx.y;
  const int t = threadIdx.x, w = t >> 6, l = t & 63;
  const int q32 = l & 31, hi = l >> 5;
  const size_t base = (size_t)bh * (S_*E_);
  const int bb = bh >> 4, h = bh & 15;

  bf16x8 qreg[2][8];
  #pragma unroll
  for (int qb2=0;qb2<2;qb2++) {
    const unsigned short* qrow = qg + base + (size_t)(qb*256 + w*64 + qb2*32 + q32)*E_;
    #pragma unroll
    for (int dc=0;dc<8;dc++)
      qreg[qb2][dc] = *reinterpret_cast<const bf16x8*>(qrow + dc*16 + hi*8);
  }

  const char* kbase = (const char*)&smem.kv.Ks[0][0];
  const char* vbase = (const char*)&smem.kv.Vs[0][0];
  const char* kp[4];
  #pragma unroll
  for (int dc=0; dc<4; dc++)
    kp[dc] = kbase + q32*256 + (((dc*2 + hi) ^ q32) & 7) * 16;
  const char* vp[2];
  #pragma unroll
  for (int kb=0; kb<2; kb++)
    vp[kb] = vbase + q32*64 + (((kb*2 + hi) ^ (q32 >> 1)) & 3) * 16;

  const unsigned short* ksrc[2]; const unsigned short* vsrc[2];
  #pragma unroll
  for (int i=0;i<2;i++) {
    int idx = i*256 + t;
    int r = idx >> 4, cb = idx & 15;
    int sb = (cb & 8) | ((cb ^ r) & 7);
    ksrc[i] = kg + base + (size_t)r*E_ + sb*8;
    int rd = idx >> 2, vb = idx & 3;
    int svb = (vb ^ (rd >> 1)) & 3;
    vsrc[i] = vtg + base + (size_t)rd*S_ + svb*8;
  }

  auto stage = [&](int bufi, int tt) {
    #pragma unroll
    for (int i=0;i<2;i++)
      __builtin_amdgcn_global_load_lds(
        (const __attribute__((address_space(1))) void*)(ksrc[i] + (size_t)tt*32*E_),
        (__attribute__((address_space(3))) void*)(&smem.kv.Ks[bufi][(i*256 + w*64)*8]),
        16, 0, 0);
    #pragma unroll
    for (int i=0;i<2;i++)
      __builtin_amdgcn_global_load_lds(
        (const __attribute__((address_space(1))) void*)(vsrc[i] + (size_t)tt*32),
        (__attribute__((address_space(3))) void*)(&smem.kv.Vs[bufi][(i*256 + w*64)*8]),
        16, 0, 0);
  };

  const f32x16 z16 = {0,0,0,0,0,0,0,0,0,0,0,0,0,0,0,0};
  f32x16 accO[8];
  #pragma unroll
  for (int i=0;i<8;i++) accO[i] = z16;
  float lsum[2] = {0.f, 0.f};

  // tile body: IDENTICAL to R17's (interleaved s0/s1 QK, SM per qb2, combined PV)
  auto process = [&](int bufi) {
    const int kOF = bufi * 8192;
    const int vOF = bufi * 8192;

    f32x16 s0 = z16, s1 = z16;
    __builtin_amdgcn_s_setprio(1);
    #pragma unroll
    for (int dc=0; dc<8; dc++) {
      bf16x8 kf = *reinterpret_cast<const bf16x8*>(kp[dc & 3] + ((dc & 4) ? 128 : 0) + kOF);
      s0 = mfma32(kf, qreg[0][dc], s0);
      s1 = mfma32(kf, qreg[1][dc], s1);
    }
    __builtin_amdgcn_s_setprio(0);

    bf16x8 pu[2][2];
    #pragma unroll
    for (int qb2=0; qb2<2; qb2++) {
      f32x16& sv = qb2 ? s1 : s0;
      float sa0 = 0.f, sa1 = 0.f;
      #pragma unroll
      for (int kb=0; kb<2; kb++) {
        union { unsigned u[4]; bf16x8 v; } uu;
        #pragma unroll
        for (int c=0; c<4; c++) {
          float pa = __builtin_amdgcn_exp2f(sv[kb*8 + c*2]);
          float pb = __builtin_amdgcn_exp2f(sv[kb*8 + c*2 + 1]);
          sa0 += pa; sa1 += pb;
          uu.u[c] = cvtpk(pa, pb);
        }
        pu[qb2][kb] = uu.v;
      }
      lsum[qb2] += sa0 + sa1;
    }

    __builtin_amdgcn_s_setprio(1);
    #pragma unroll
    for (int dc=0; dc<4; dc++)
      #pragma unroll
      for (int kb=0; kb<2; kb++) {
        bf16x8 vf = *reinterpret_cast<const bf16x8*>(vp[kb] + dc*2048 + vOF);
        accO[dc]   = mfma32(vf, pu[0][kb], accO[dc]);
        accO[4+dc] = mfma32(vf, pu[1][kb], accO[4+dc]);
      }
    __builtin_amdgcn_s_setprio(0);
  };

  stage(0, 0);   // buffers 0,1 <- tiles 0,1
  stage(1, 1);
  __syncthreads();

  #pragma unroll 2
  for (int it = 0; it < 16; ++it) {
    const int set = it & 1;
    // issue-early: the other pair's buffers were last read in iteration it-1 (before the barrier)
    if (it < 15) {
      stage((set^1)*2,     2*it + 2);
      stage((set^1)*2 + 1, 2*it + 3);
    }
    process(set*2);        // tile 2*it
    process(set*2 + 1);    // tile 2*it+1
    __syncthreads();       // drains stages + protects swap (one barrier per 2 tiles)
  }

  // ---- epilogue: per-wave LDS transpose (aliased over dead K/V) -> coalesced 512B row stores ----
  const int cl = l & 31, rh = l >> 5;
  #pragma unroll
  for (int qb2=0; qb2<2; qb2++) {
    float lt = lsum[qb2] + __shfl_xor(lsum[qb2], 32);
    float inv = 1.0f / lt;
    #pragma unroll
    for (int dc=0;dc<4;dc++)
      #pragma unroll
      for (int rq=0;rq<4;rq++) {
        float4 o4;
        o4.x = accO[qb2*4+dc][rq*4+0]*inv;
        o4.y = accO[qb2*4+dc][rq*4+1]*inv;
        o4.z = accO[qb2*4+dc][rq*4+2]*inv;
        o4.w = accO[qb2*4+dc][rq*4+3]*inv;
        *reinterpret_cast<float4*>(&smem.Tr[w][q32][dc*32 + rq*8 + hi*4]) = o4;
      }
    __syncthreads();   // RAW fence: scatters visible before gather
    #pragma unroll
    for (int i=0;i<16;i++) {
      int r = i*2 + rh;
      int s = qb*256 + w*64 + qb2*32 + r;
      float4 o4 = *reinterpret_cast<const float4*>(&smem.Tr[w][r][cl*4]);
      *reinterpret_cast<float4*>(out + ((size_t)(bb*S_ + s)*H_ + h)*E_ + cl*4) = o4;
    }
    __syncthreads();   // WAR fence before next qb2 scatter
  }
}

extern "C" void kernel_launch(void* const* d_in, const int* in_sizes, int n_in,
                              void* d_out, int out_size, void* d_ws, size_t ws_size,
                              hipStream_t stream) {
  const float* seq = (const float*)d_in[0];
  const float* wq  = (const float*)d_in[1];
  const float* bq  = (const float*)d_in[2];
  float* out = (float*)d_out;
  char* ws = (char*)d_ws;
  size_t off = 0;
  unsigned short* seqb = (unsigned short*)(ws + off); off += (size_t)M_*E_*2;
  unsigned short* wb   = (unsigned short*)(ws + off); off += (size_t)F_*E_*2;
  float* ctab = (float*)(ws + off); off += (size_t)S_*64*4;
  float* stab = (float*)(ws + off); off += (size_t)S_*64*4;
  unsigned short* qbuf = (unsigned short*)(ws + off); off += (size_t)B_*H_*S_*E_*2;
  unsigned short* kbuf = (unsigned short*)(ws + off); off += (size_t)B_*H_*S_*E_*2;
  unsigned short* vtbuf= (unsigned short*)(ws + off); off += (size_t)B_*H_*S_*E_*2;

  prep_kernel<<<dim3(1024), dim3(256), 0, stream>>>(seq, wq, seqb, wb, ctab, stab);
  qkv_gemm_kernel<<<dim3(64, 48), dim3(256), 0, stream>>>(seqb, wb, bq, ctab, stab, qbuf, kbuf, vtbuf);
  attn_kernel<<<dim3(128, 4), dim3(256), 0, stream>>>(qbuf, kbuf, vtbuf, out);
}

// Round 19
// 118.937 us; speedup vs baseline: 1.2467x; 1.2467x over previous
//
#include <hip/hip_runtime.h>
#include <hip/hip_bf16.h>
#include <math.h>

typedef __attribute__((ext_vector_type(8))) short bf16x8;
typedef __attribute__((ext_vector_type(4))) float f32x4;
typedef __attribute__((ext_vector_type(16))) float f32x16;

#define B_ 8
#define S_ 1024
#define E_ 128
#define H_ 16
#define M_ (B_*S_)
#define F_ (3*H_*E_)

__device__ __forceinline__ unsigned short f2b(float x) {
  __hip_bfloat16 h = __float2bfloat16(x);
  return *reinterpret_cast<unsigned short*>(&h);
}

__device__ __forceinline__ f32x4 mfma16(bf16x8 a, bf16x8 b, f32x4 c) {
  return __builtin_amdgcn_mfma_f32_16x16x32_bf16(a, b, c, 0, 0, 0);
}
__device__ __forceinline__ f32x16 mfma32(bf16x8 a, bf16x8 b, f32x16 c) {
  return __builtin_amdgcn_mfma_f32_32x32x16_bf16(a, b, c, 0, 0, 0);
}
__device__ __forceinline__ unsigned cvtpk(float a, float b) {
  unsigned r; asm("v_cvt_pk_bf16_f32 %0, %1, %2" : "=v"(r) : "v"(a), "v"(b)); return r;
}

// ---------------- prep: fp32->bf16 + rope tables ----------------
__global__ __launch_bounds__(256) void prep_kernel(
    const float* __restrict__ seq, const float* __restrict__ wq,
    unsigned short* __restrict__ seqb, unsigned short* __restrict__ wb,
    float* __restrict__ ctab, float* __restrict__ stab)
{
  int i = blockIdx.x * 256 + threadIdx.x;
  if (i < M_*E_/4) {
    float4 v = reinterpret_cast<const float4*>(seq)[i];
    ushort4 o; o.x = f2b(v.x); o.y = f2b(v.y); o.z = f2b(v.z); o.w = f2b(v.w);
    reinterpret_cast<ushort4*>(seqb)[i] = o;
  }
  if (i < F_*E_/4) {
    float4 v = reinterpret_cast<const float4*>(wq)[i];
    ushort4 o; o.x = f2b(v.x); o.y = f2b(v.y); o.z = f2b(v.z); o.w = f2b(v.w);
    reinterpret_cast<ushort4*>(wb)[i] = o;
  }
  if (i < S_*64) {
    int s = i >> 6, e = i & 63;
    double ang = (double)s * pow(10000.0, -(double)e / 64.0);
    ctab[i] = (float)cos(ang);
    stab[i] = (float)sin(ang);
  }
}

// ---------------- QKV GEMM + bias + rope -> Q,K (B,H,S,E), V^T (B,H,E,S) ----------------
// K pre-scaled by (1/sqrt(128)) * log2(e) so attention uses exp2 directly.
// V^T stored with kv-index bits 2<->3 swapped within each aligned 32-group (exchange-free PV repack).
__global__ __launch_bounds__(256) void qkv_gemm_kernel(
    const unsigned short* __restrict__ Ab, const unsigned short* __restrict__ Wb,
    const float* __restrict__ bias, const float* __restrict__ ctab, const float* __restrict__ stab,
    unsigned short* __restrict__ qo, unsigned short* __restrict__ ko, unsigned short* __restrict__ vt)
{
  __shared__ union QSMem {
    struct { unsigned short A[128*128]; unsigned short W[128*128]; } s;  // 64 KB, GEMM phase
    unsigned short Tp[128][136];                                         // 34.8 KB, V-transpose
  } sm;
  const int bm = blockIdx.x, bn = blockIdx.y;
  const int t = threadIdx.x;
  const int w = t >> 6, l = t & 63, lc = l & 15, g = l >> 4;

  #pragma unroll
  for (int i = 0; i < 8; ++i) {
    int c = i*256 + t;
    int row = c >> 4, cb = c & 15;
    int sb = (cb & 8) | ((cb ^ row) & 7);
    __builtin_amdgcn_global_load_lds(
      (const __attribute__((address_space(1))) void*)(Ab + (size_t)(bm*128+row)*128 + sb*8),
      (__attribute__((address_space(3))) void*)(&sm.s.A[c*8]), 16, 0, 0);
    __builtin_amdgcn_global_load_lds(
      (const __attribute__((address_space(1))) void*)(Wb + (size_t)(bn*128+row)*128 + sb*8),
      (__attribute__((address_space(3))) void*)(&sm.s.W[c*8]), 16, 0, 0);
  }
  __syncthreads();

  const f32x4 zero = {0.f, 0.f, 0.f, 0.f};
  f32x4 acc[2][8];
  #pragma unroll
  for (int mi=0;mi<2;mi++)
    #pragma unroll
    for (int nj=0;nj<8;nj++) acc[mi][nj] = zero;

  #pragma unroll
  for (int ks = 0; ks < 4; ++ks) {
    const int B0 = ks*4 + g;
    const int slot = (B0 & 8) | ((B0 ^ lc) & 7);
    bf16x8 a[2], b[8];
    #pragma unroll
    for (int mi=0;mi<2;mi++)
      a[mi] = *reinterpret_cast<const bf16x8*>(&sm.s.A[(w*32 + mi*16 + lc)*128 + slot*8]);
    #pragma unroll
    for (int nj=0;nj<8;nj++)
      b[nj] = *reinterpret_cast<const bf16x8*>(&sm.s.W[(nj*16 + lc)*128 + slot*8]);
    #pragma unroll
    for (int mi=0;mi<2;mi++)
      #pragma unroll
      for (int nj=0;nj<8;nj++)
        acc[mi][nj] = mfma16(a[mi], b[nj], acc[mi][nj]);
  }

  float bv[8];
  #pragma unroll
  for (int nj=0;nj<8;nj++) bv[nj] = bias[bn*128 + nj*16 + lc];

  const int c3 = bn >> 4, h = bn & 15;
  if (c3 < 2) {
    unsigned short* dst = (c3 == 0) ? qo : ko;
    const float mul = (c3 == 1) ? 0.12751742f : 1.0f;
    #pragma unroll
    for (int mi=0;mi<2;mi++)
      #pragma unroll
      for (int r=0;r<4;r++) {
        int mrow = bm*128 + w*32 + mi*16 + g*4 + r;
        int bb = mrow >> 10, s = mrow & 1023;
        size_t ob = ((size_t)(bb*H_ + h)*S_ + s)*E_;
        #pragma unroll
        for (int nj=0;nj<4;nj++) {
          int e1 = nj*16 + lc;
          float x1 = acc[mi][nj][r]   + bv[nj];
          float x2 = acc[mi][nj+4][r] + bv[nj+4];
          float cs = ctab[s*64 + e1], sn = stab[s*64 + e1];
          dst[ob + e1]      = f2b((x1*cs - x2*sn) * mul);
          dst[ob + e1 + 64] = f2b((x1*sn + x2*cs) * mul);
        }
      }
  } else {
    __syncthreads();
    const int gsw = ((g & 1) << 1) | (g >> 1);   // swap kv bits 2<->3 (within 32-group)
    #pragma unroll
    for (int mi=0;mi<2;mi++)
      #pragma unroll
      for (int nj=0;nj<8;nj++)
        #pragma unroll
        for (int r=0;r<4;r++)
          sm.Tp[nj*16 + lc][w*32 + mi*16 + gsw*4 + r] = f2b(acc[mi][nj][r] + bv[nj]);
    __syncthreads();
    int bb = bm >> 3, sb2 = (bm & 7) * 128;
    #pragma unroll
    for (int i=0;i<8;i++) {
      int cidx = t + i*256, e = cidx >> 4, sc = cidx & 15;
      *reinterpret_cast<bf16x8*>(&vt[((size_t)(bb*H_ + h)*E_ + e)*S_ + sb2 + sc*8]) =
          *reinterpret_cast<const bf16x8*>(&sm.Tp[e][sc*8]);
    }
  }
}

// ---------------- flash attention: 4 waves x 64 q-rows, KVBLK=32, static-max softmax ----------------
// R13/R14/R17 verified structure: R10 main loop + union-aliased LDS-transpose epilogue.
__global__ __launch_bounds__(256, 2) void attn_kernel(
    const unsigned short* __restrict__ qg, const unsigned short* __restrict__ kg,
    const unsigned short* __restrict__ vtg, float* __restrict__ out)
{
  __shared__ union SMem {
    struct { unsigned short Ks[2][32*128]; unsigned short Vs[2][128*32]; } kv;  // 32768 B, main loop
    float Tr[4][32][132];                                                       // 67584 B, epilogue
  } smem;
  const int bh = blockIdx.x, qb = blockIdx.y;
  const int t = threadIdx.x, w = t >> 6, l = t & 63;
  const int q32 = l & 31, hi = l >> 5;
  const size_t base = (size_t)bh * (S_*E_);
  const int bb = bh >> 4, h = bh & 15;

  bf16x8 qreg[2][8];
  #pragma unroll
  for (int qb2=0;qb2<2;qb2++) {
    const unsigned short* qrow = qg + base + (size_t)(qb*256 + w*64 + qb2*32 + q32)*E_;
    #pragma unroll
    for (int dc=0;dc<8;dc++)
      qreg[qb2][dc] = *reinterpret_cast<const bf16x8*>(qrow + dc*16 + hi*8);
  }

  const char* kbase = (const char*)&smem.kv.Ks[0][0];
  const char* vbase = (const char*)&smem.kv.Vs[0][0];
  const char* kp[4];
  #pragma unroll
  for (int dc=0; dc<4; dc++)
    kp[dc] = kbase + q32*256 + (((dc*2 + hi) ^ q32) & 7) * 16;
  const char* vp[2];
  #pragma unroll
  for (int kb=0; kb<2; kb++)
    vp[kb] = vbase + q32*64 + (((kb*2 + hi) ^ (q32 >> 1)) & 3) * 16;

  const unsigned short* ksrc[2]; const unsigned short* vsrc[2];
  #pragma unroll
  for (int i=0;i<2;i++) {
    int idx = i*256 + t;
    int r = idx >> 4, cb = idx & 15;
    int sb = (cb & 8) | ((cb ^ r) & 7);
    ksrc[i] = kg + base + (size_t)r*E_ + sb*8;
    int rd = idx >> 2, vb = idx & 3;
    int svb = (vb ^ (rd >> 1)) & 3;
    vsrc[i] = vtg + base + (size_t)rd*S_ + svb*8;
  }

  auto stage = [&](int bufi, int tt) {
    #pragma unroll
    for (int i=0;i<2;i++)
      __builtin_amdgcn_global_load_lds(
        (const __attribute__((address_space(1))) void*)(ksrc[i] + (size_t)tt*32*E_),
        (__attribute__((address_space(3))) void*)(&smem.kv.Ks[bufi][(i*256 + w*64)*8]),
        16, 0, 0);
    #pragma unroll
    for (int i=0;i<2;i++)
      __builtin_amdgcn_global_load_lds(
        (const __attribute__((address_space(1))) void*)(vsrc[i] + (size_t)tt*32),
        (__attribute__((address_space(3))) void*)(&smem.kv.Vs[bufi][(i*256 + w*64)*8]),
        16, 0, 0);
  };

  const f32x16 z16 = {0,0,0,0,0,0,0,0,0,0,0,0,0,0,0,0};
  f32x16 accO[8];
  #pragma unroll
  for (int i=0;i<8;i++) accO[i] = z16;
  float lsum[2] = {0.f, 0.f};

  stage(0, 0);
  __syncthreads();

  #pragma unroll 2
  for (int tt = 0; tt < 32; ++tt) {
    const int cur = tt & 1;
    const int kOF = cur * 8192;
    const int vOF = cur * 8192;

    if (tt < 31) stage(cur ^ 1, tt + 1);

    f32x16 s0 = z16, s1 = z16;
    __builtin_amdgcn_s_setprio(1);
    #pragma unroll
    for (int dc=0; dc<8; dc++) {
      bf16x8 kf = *reinterpret_cast<const bf16x8*>(kp[dc & 3] + ((dc & 4) ? 128 : 0) + kOF);
      s0 = mfma32(kf, qreg[0][dc], s0);
      s1 = mfma32(kf, qreg[1][dc], s1);
    }
    __builtin_amdgcn_s_setprio(0);

    bf16x8 pu[2][2];
    #pragma unroll
    for (int qb2=0; qb2<2; qb2++) {
      f32x16& sv = qb2 ? s1 : s0;
      float sa0 = 0.f, sa1 = 0.f;
      #pragma unroll
      for (int kb=0; kb<2; kb++) {
        union { unsigned u[4]; bf16x8 v; } uu;
        #pragma unroll
        for (int c=0; c<4; c++) {
          float pa = __builtin_amdgcn_exp2f(sv[kb*8 + c*2]);
          float pb = __builtin_amdgcn_exp2f(sv[kb*8 + c*2 + 1]);
          sa0 += pa; sa1 += pb;
          uu.u[c] = cvtpk(pa, pb);
        }
        pu[qb2][kb] = uu.v;
      }
      lsum[qb2] += sa0 + sa1;
    }

    __builtin_amdgcn_s_setprio(1);
    #pragma unroll
    for (int dc=0; dc<4; dc++)
      #pragma unroll
      for (int kb=0; kb<2; kb++) {
        bf16x8 vf = *reinterpret_cast<const bf16x8*>(vp[kb] + dc*2048 + vOF);
        accO[dc]   = mfma32(vf, pu[0][kb], accO[dc]);
        accO[4+dc] = mfma32(vf, pu[1][kb], accO[4+dc]);
      }
    __builtin_amdgcn_s_setprio(0);

    __syncthreads();
  }

  // ---- epilogue: per-wave LDS transpose (aliased over dead K/V) -> coalesced 512B row stores ----
  const int cl = l & 31, rh = l >> 5;
  #pragma unroll
  for (int qb2=0; qb2<2; qb2++) {
    float lt = lsum[qb2] + __shfl_xor(lsum[qb2], 32);
    float inv = 1.0f / lt;
    #pragma unroll
    for (int dc=0;dc<4;dc++)
      #pragma unroll
      for (int rq=0;rq<4;rq++) {
        float4 o4;
        o4.x = accO[qb2*4+dc][rq*4+0]*inv;
        o4.y = accO[qb2*4+dc][rq*4+1]*inv;
        o4.z = accO[qb2*4+dc][rq*4+2]*inv;
        o4.w = accO[qb2*4+dc][rq*4+3]*inv;
        *reinterpret_cast<float4*>(&smem.Tr[w][q32][dc*32 + rq*8 + hi*4]) = o4;
      }
    __syncthreads();
    #pragma unroll
    for (int i=0;i<16;i++) {
      int r = i*2 + rh;
      int s = qb*256 + w*64 + qb2*32 + r;
      float4 o4 = *reinterpret_cast<const float4*>(&smem.Tr[w][r][cl*4]);
      *reinterpret_cast<float4*>(out + ((size_t)(bb*S_ + s)*H_ + h)*E_ + cl*4) = o4;
    }
    __syncthreads();
  }
}

extern "C" void kernel_launch(void* const* d_in, const int* in_sizes, int n_in,
                              void* d_out, int out_size, void* d_ws, size_t ws_size,
                              hipStream_t stream) {
  const float* seq = (const float*)d_in[0];
  const float* wq  = (const float*)d_in[1];
  const float* bq  = (const float*)d_in[2];
  float* out = (float*)d_out;
  char* ws = (char*)d_ws;
  size_t off = 0;
  unsigned short* seqb = (unsigned short*)(ws + off); off += (size_t)M_*E_*2;
  unsigned short* wb   = (unsigned short*)(ws + off); off += (size_t)F_*E_*2;
  float* ctab = (float*)(ws + off); off += (size_t)S_*64*4;
  float* stab = (float*)(ws + off); off += (size_t)S_*64*4;
  unsigned short* qbuf = (unsigned short*)(ws + off); off += (size_t)B_*H_*S_*E_*2;
  unsigned short* kbuf = (unsigned short*)(ws + off); off += (size_t)B_*H_*S_*E_*2;
  unsigned short* vtbuf= (unsigned short*)(ws + off); off += (size_t)B_*H_*S_*E_*2;

  prep_kernel<<<dim3(1024), dim3(256), 0, stream>>>(seq, wq, seqb, wb, ctab, stab);
  qkv_gemm_kernel<<<dim3(64, 48), dim3(256), 0, stream>>>(seqb, wb, bq, ctab, stab, qbuf, kbuf, vtbuf);
  attn_kernel<<<dim3(128, 4), dim3(256), 0, stream>>>(qbuf, kbuf, vtbuf, out);
}